// Round 1
// baseline (228.734 us; speedup 1.0000x reference)
//
#include <hip/hip_runtime.h>

#define T_TOK 32768   // B*S
#define NQ    8
#define FFN   2048
#define EMB   512
#define BM    128
#define BN    128
#define BK    64
#define NCHUNK (FFN / BK)   // 32

typedef __attribute__((ext_vector_type(8))) short  short8;
typedef __attribute__((ext_vector_type(4))) float  float4v;

__device__ __forceinline__ unsigned short f2bf(float f) {
  unsigned int u = __float_as_uint(f);
  u += 0x7fffu + ((u >> 16) & 1u);
  return (unsigned short)(u >> 16);
}

// ---------------------------------------------------------------------------
// Prep: qc = bf16(cos(x)*cos(theta))  [T_TOK x 8]
//       w1t = bf16(W1^T)              [FFN x 8]
//       w2t = bf16(W2^T)              [EMB x FFN]
// ---------------------------------------------------------------------------
__global__ void prep_kernel(const float* __restrict__ x,
                            const float* __restrict__ theta,
                            const float* __restrict__ W1,
                            const float* __restrict__ W2,
                            unsigned short* __restrict__ qc,
                            unsigned short* __restrict__ w1t,
                            unsigned short* __restrict__ w2t) {
  int idx = blockIdx.x * blockDim.x + threadIdx.x;
  if (idx < EMB * FFN) {
    int n = idx >> 11;          // / FFN
    int k = idx & (FFN - 1);
    w2t[idx] = f2bf(W2[k * EMB + n]);
  }
  int i2 = idx - EMB * FFN;
  if (i2 >= 0 && i2 < T_TOK * NQ) {
    qc[i2] = f2bf(cosf(x[i2]) * cosf(theta[i2 & 7]));
  }
  int i3 = i2 - T_TOK * NQ;
  if (i3 >= 0 && i3 < FFN * NQ) {
    int f = i3 >> 3, i = i3 & 7;
    w1t[i3] = f2bf(W1[i * FFN + f]);
  }
}

// ---------------------------------------------------------------------------
// Fused: out[tok, n] = relu(qc @ W1 + b1) @ W2 + b2, h kept in LDS per chunk.
// ---------------------------------------------------------------------------
__global__ __launch_bounds__(256, 2) void ffq_main(
    const unsigned short* __restrict__ qc,
    const unsigned short* __restrict__ w1t,
    const unsigned short* __restrict__ w2t,
    const float* __restrict__ b1,
    const float* __restrict__ b2,
    float* __restrict__ out) {

  // h tile, padded +8 bf16 -> row stride 144 B -> 2-way (free) frag reads
  __shared__ unsigned short h_lds[BM][BK + 8];
  // W2^T chunk [BN rows x BK], 16B-chunk XOR swizzle (c ^ (row&7)) on content
  __shared__ unsigned short w2_lds[BN * BK];

  const int tid  = threadIdx.x;
  const int wave = tid >> 6;
  const int lane = tid & 63;
  const int l15  = lane & 15;
  const int quad = lane >> 4;
  const int tok0 = blockIdx.x * BM;
  const int n0   = blockIdx.y * BN;
  const int wr   = wave >> 1;   // GEMM2 wave row (64 tokens)
  const int wc   = wave & 1;    // GEMM2 wave col (64 emb)

  // GEMM1 A fragments (constant over K-loop): wave owns h rows [32w, 32w+32).
  // 16x16x32 A layout: m = lane&15, k = quad*8 + j; valid K is 0..7 -> only
  // quad 0 carries data, quads 1..3 are the K-padding (zeros).
  short8 a1[2];
  a1[0] = (short8){0,0,0,0,0,0,0,0};
  a1[1] = (short8){0,0,0,0,0,0,0,0};
  if (lane < 16) {
    a1[0] = *(const short8*)(qc + (size_t)(tok0 + 32 * wave + lane) * NQ);
    a1[1] = *(const short8*)(qc + (size_t)(tok0 + 32 * wave + 16 + lane) * NQ);
  }

  float4v acc[4][4];
#pragma unroll
  for (int i = 0; i < 4; ++i)
#pragma unroll
    for (int j = 0; j < 4; ++j)
      acc[i][j] = (float4v){0.f, 0.f, 0.f, 0.f};

  for (int kc = 0; kc < NCHUNK; ++kc) {
    const int k0 = kc * BK;

    __syncthreads();  // prev chunk's LDS readers done

    // ---- async stage W2^T chunk -> w2_lds (global_load_lds, 16 B/lane) ----
    {
      const int r = tid >> 3;   // row within 32-row group
      const int c = tid & 7;    // stored 16B-chunk index
#pragma unroll
      for (int issue = 0; issue < 4; ++issue) {
        const int row    = issue * 32 + r;        // local n, 0..127
        const int gchunk = c ^ (row & 7);         // XOR swizzle source pick
        const unsigned short* g =
            w2t + (size_t)(n0 + row) * FFN + k0 + gchunk * 8;
        unsigned short* l = &w2_lds[issue * 2048 + tid * 8];
        __builtin_amdgcn_global_load_lds(
            (const __attribute__((address_space(1))) void*)g,
            (__attribute__((address_space(3))) void*)l, 16, 0, 0);
      }
    }

    // ---- GEMM1 (K=8 padded to 32): h[32w..32w+32, k0..k0+64) ----
#pragma unroll
    for (int kt = 0; kt < 4; ++kt) {
      short8 b1f = (short8){0,0,0,0,0,0,0,0};
      if (lane < 16) {
        b1f = *(const short8*)(w1t + (size_t)(k0 + kt * 16 + lane) * NQ);
      }
      float4v c0 = {0.f, 0.f, 0.f, 0.f};
      float4v c1 = {0.f, 0.f, 0.f, 0.f};
      c0 = __builtin_amdgcn_mfma_f32_16x16x32_bf16(a1[0], b1f, c0, 0, 0, 0);
      c1 = __builtin_amdgcn_mfma_f32_16x16x32_bf16(a1[1], b1f, c1, 0, 0, 0);
      const float bv   = b1[k0 + kt * 16 + l15];
      const int   colk = kt * 16 + l15;
#pragma unroll
      for (int r = 0; r < 4; ++r) {
        float v0 = c0[r] + bv; v0 = v0 > 0.f ? v0 : 0.f;
        float v1 = c1[r] + bv; v1 = v1 > 0.f ? v1 : 0.f;
        h_lds[32 * wave + quad * 4 + r][colk]      = f2bf(v0);
        h_lds[32 * wave + 16 + quad * 4 + r][colk] = f2bf(v1);
      }
    }

    __syncthreads();  // h visible; vmcnt(0) drained -> w2_lds ready

    // ---- GEMM2: acc += h_tile @ w2_chunk ----
#pragma unroll
    for (int ks = 0; ks < 2; ++ks) {
      short8 af[4], bf[4];
#pragma unroll
      for (int mt = 0; mt < 4; ++mt) {
        const int m = wr * 64 + mt * 16 + l15;
        af[mt] = *(const short8*)&h_lds[m][ks * 32 + quad * 8];
      }
#pragma unroll
      for (int nt = 0; nt < 4; ++nt) {
        const int n  = wc * 64 + nt * 16 + l15;
        const int sc = (ks * 4 + quad) ^ (n & 7);   // undo XOR swizzle
        bf[nt] = *(const short8*)&w2_lds[n * BK + sc * 8];
      }
#pragma unroll
      for (int mt = 0; mt < 4; ++mt)
#pragma unroll
        for (int nt = 0; nt < 4; ++nt)
          acc[mt][nt] = __builtin_amdgcn_mfma_f32_16x16x32_bf16(
              af[mt], bf[nt], acc[mt][nt], 0, 0, 0);
    }
  }

  // ---- epilogue: + b2, fp32 store ----
#pragma unroll
  for (int nt = 0; nt < 4; ++nt) {
    const int col = n0 + wc * 64 + nt * 16 + l15;
    const float bv = b2[col];
#pragma unroll
    for (int mt = 0; mt < 4; ++mt) {
      const int row0 = tok0 + wr * 64 + mt * 16 + quad * 4;
#pragma unroll
      for (int r = 0; r < 4; ++r) {
        out[(size_t)(row0 + r) * EMB + col] = acc[mt][nt][r] + bv;
      }
    }
  }
}

extern "C" void kernel_launch(void* const* d_in, const int* in_sizes, int n_in,
                              void* d_out, int out_size, void* d_ws, size_t ws_size,
                              hipStream_t stream) {
  const float* x     = (const float*)d_in[0];
  const float* theta = (const float*)d_in[1];
  const float* W1    = (const float*)d_in[2];
  const float* b1    = (const float*)d_in[3];
  const float* W2    = (const float*)d_in[4];
  const float* b2    = (const float*)d_in[5];
  float* out = (float*)d_out;

  unsigned short* qc  = (unsigned short*)d_ws;   // 262144 bf16
  unsigned short* w1t = qc + T_TOK * NQ;         // 16384 bf16
  unsigned short* w2t = w1t + FFN * NQ;          // 1048576 bf16

  const int total = EMB * FFN + T_TOK * NQ + FFN * NQ;  // 1327104
  prep_kernel<<<(total + 255) / 256, 256, 0, stream>>>(x, theta, W1, W2,
                                                       qc, w1t, w2t);

  dim3 grid(T_TOK / BM, EMB / BN);  // (256, 4)
  ffq_main<<<grid, 256, 0, stream>>>(qc, w1t, w2t, b1, b2, out);
}